// Round 22
// baseline (22.177 us; speedup 1.0000x reference)
//
#include <hip/hip_runtime.h>
#include <math.h>

#pragma clang fp contract(off)

namespace {
constexpr int P_STR  = 16;   // strokes per image
constexpr int K_KNOT = 8;
constexpr int H = 384;
constexpr int W = 384;
constexpr int BH = 64;
constexpr int BW = 64;
constexpr int TW = 32;       // tile width (cols)
constexpr int TH = 8;        // tile height (rows)
constexpr int NTX = W / TW;  // 12
constexpr int NTY = H / TH;  // 48
constexpr int NTILES = NTX * NTY;        // 576 per image
constexpr int BLK_PER_IMG = 288;         // persistent blocks per image
constexpr int TILES_PER_BLK = NTILES / BLK_PER_IMG;  // 2
constexpr int PAD = 66;      // logical padded extent (64 + 2)
constexpr int LDSP = 67;     // pitch: odd -> coprime with 32 banks
constexpr int AFLOATS = 66 * LDSP + 2;   // 4424 floats
constexpr int PARAM_F = 8;   // floats per stroke param slot
}

// ---- faithful port of glibc sysdeps/ieee754/flt-32/s_atanf.c (fdlibm) ----
__device__ __forceinline__ float fdlibm_atanf_plain(float x)
{
#pragma clang fp contract(off)
    const float atanhi0 = 4.6364760399e-01f, atanhi1 = 7.8539812565e-01f,
                atanhi2 = 9.8279368877e-01f, atanhi3 = 1.5707962513e+00f;
    const float atanlo0 = 5.0121582440e-09f, atanlo1 = 3.7748947079e-08f,
                atanlo2 = 3.4473217170e-08f, atanlo3 = 7.5497894159e-08f;
    const float aT0 = 3.3333328366e-01f, aT1 = -1.9999158382e-01f,
                aT2 = 1.4253635705e-01f, aT3 = -1.0648017377e-01f,
                aT4 = 6.1687607318e-02f;
    const float one = 1.0f;

    const int hx = __float_as_int(x);
    const int ix = hx & 0x7fffffff;
    int id;
    if (ix >= 0x4c800000) {           // |x| >= 2^26
        if (ix > 0x7f800000) return x + x;   // NaN
        return (hx > 0) ? (atanhi3 + atanlo3) : (-atanhi3 - atanlo3);
    }
    if (ix < 0x3ee00000) {            // |x| < 0.4375
        if (ix < 0x39800000) return x;       // |x| < 2^-12
        id = -1;
    } else {
        x = fabsf(x);
        if (ix < 0x3f980000) {        // |x| < 1.1875
            if (ix < 0x3f300000) {    // 7/16 <= |x| < 11/16
                id = 0; x = (2.0f * x - one) / (2.0f + x);
            } else {                  // 11/16 <= |x| < 19/16
                id = 1; x = (x - one) / (x + one);
            }
        } else {
            if (ix < 0x401c0000) {    // |x| < 2.4375
                id = 2; x = (x - 1.5f) / (one + 1.5f * x);
            } else {                  // 2.4375 <= |x|
                id = 3; x = -1.0f / x;
            }
        }
    }
    const float z = x * x;
    const float w = z * z;
    const float s1 = z * (aT0 + w * (aT2 + w * aT4));
    const float s2 = w * (aT1 + w * aT3);
    if (id < 0) return x - x * (s1 + s2);
    const float ahi = (id == 0) ? atanhi0 : (id == 1) ? atanhi1 : (id == 2) ? atanhi2 : atanhi3;
    const float alo = (id == 0) ? atanlo0 : (id == 1) ? atanlo1 : (id == 2) ? atanlo2 : atanlo3;
    const float zz = ahi - ((x * (s1 + s2) - alo) - x);
    return (hx < 0) ? -zz : zz;
}

// ---- faithful port of glibc sysdeps/ieee754/flt-32/e_atan2f.c (fdlibm) ----
__device__ __forceinline__ float fdlibm_atan2f_plain(float y, float x)
{
#pragma clang fp contract(off)
    const float pi_o_2 = 1.5707963705e+00f;   // 0x3FC90FDB
    const float pi_    = 3.1415927410e+00f;   // 0x40490FDB
    const float pi_lo  = -8.7422776573e-08f;  // 0xB3BBBD2E

    const int hx = __float_as_int(x), hy = __float_as_int(y);
    const int ix = hx & 0x7fffffff, iy = hy & 0x7fffffff;
    if (ix > 0x7f800000 || iy > 0x7f800000) return x + y;   // NaN
    if (hx == 0x3f800000) return fdlibm_atanf_plain(y);     // x == 1.0
    int m = ((hy >> 31) & 1) | ((hx >> 30) & 2);

    if (iy == 0) {
        switch (m) {
            case 0: case 1: return y;
            case 2: return pi_;
            default: return -pi_;
        }
    }
    if (ix == 0) return (hy < 0) ? -pi_o_2 : pi_o_2;
    if (ix == 0x7f800000) {
        if (iy == 0x7f800000) {
            switch (m) {
                case 0: return  pi_o_2 * 0.5f;
                case 1: return -pi_o_2 * 0.5f;
                case 2: return  3.0f * pi_o_2 * 0.5f;
                default: return -3.0f * pi_o_2 * 0.5f;
            }
        }
        switch (m) {
            case 0: return 0.0f;
            case 1: return -0.0f;
            case 2: return pi_;
            default: return -pi_;
        }
    }
    if (iy == 0x7f800000) return (hy < 0) ? -pi_o_2 : pi_o_2;

    const int k = (iy - ix) >> 23;
    float z;
    if (k > 26) {                    // |y/x| > 2^26
        z = pi_o_2 + 0.5f * pi_lo;
        m &= 1;
    } else if (hx < 0 && k < -26) {  // |y|/x < -2^26
        z = 0.0f;
    } else {
        z = fdlibm_atanf_plain(fabsf(y / x));
    }
    switch (m) {
        case 0: return z;
        case 1: return -z;
        case 2: return pi_ - (z - pi_lo);
        default: return (z - pi_lo) - pi_;
    }
}

// ==== fused: phase A (wave 0) ∥ alpha staging (waves 1-3), then composite ====
__global__ __launch_bounds__(256) void blit_fused(
    const float* __restrict__ images, const float* __restrict__ knot_t,
    const float* __restrict__ a_,     const float* __restrict__ b_,
    const float* __restrict__ c2_,    const float* __restrict__ d3_,
    const float* __restrict__ colors, const float* __restrict__ ts,
    const float* __restrict__ brush,  float* __restrict__ out)
{
#pragma clang fp contract(off)
    __shared__ float sP[P_STR * PARAM_F];            // 128 floats
    __shared__ __align__(8) float s_alpha[AFLOATS];  // 4424 floats, pitch 67

    const int n   = blockIdx.z;
    const int L   = blockIdx.x;          // 0..287
    const int tid = threadIdx.x;

    const float c3 = colors[n * 4 + 3];

    // ---- Phase A on wave 0 lanes 0..15 (BIT-LOCKED R13 math, unchanged) ----
    if (tid < P_STR) {
        const int p = tid;
        const float t = ts[p];
        int ins = 0;
        #pragma unroll
        for (int i = 0; i < K_KNOT; ++i) ins += (knot_t[i] <= t) ? 1 : 0;
        const int idx = min(max(ins - 1, 0), K_KNOT - 2);
        const float f = t - knot_t[idx];

        const int base = (n * (K_KNOT - 1) + idx) * 3;
        const float C3INV = 0.3333333432674408f;   // 0x3EAAAAAB
        float q[3], qd[3];
        #pragma unroll
        for (int j = 0; j < 3; ++j) {
            const float aj = a_[base + j], bj = b_[base + j];
            const float cj = c2_[base + j], dj = d3_[base + j];
            const float inner = cj * 0.5f + (dj * f) * C3INV;
            q[j]  = aj + (bj + inner * f) * f;
            qd[j] = bj + (cj + dj * f) * f;
        }
        const float x = q[0], y = q[1], z = q[2];
        const float s = fminf(fmaxf(z, 0.001f), 1.0f);

        const float apos = fdlibm_atan2f_plain(qd[1], qd[0]);
        const float thf  = -apos;
        const float ct_  = (float)cos((double)thf);
        const float st_  = (float)sin((double)thf);

        float* P = sP + p * PARAM_F;
        P[0] = x; P[1] = y; P[2] = 1.0f / s;   // reciprocal rounded ONCE
        P[3] = ct_; P[4] = st_;
        P[5] = (z > 0.0f) ? 1.0f : 0.0f;
    }

    // ---- alpha staging on waves 1..3 (independent of params; overlaps trig) ----
    if (tid >= 64) {
        for (int i = tid - 64; i < AFLOATS; i += 192) {
            const int v = i / LDSP;
            const int u = i - v * LDSP;
            float val = 0.0f;
            if ((unsigned)(v - 1) < (unsigned)BH && (unsigned)(u - 1) < (unsigned)BW)
                val = brush[3 * BH * BW + (v - 1) * BW + (u - 1)] * c3;
            s_alpha[i] = val;
        }
    }

    // ---- image PREFETCH for both tiles (independent of LDS; overlaps
    //      staging + Phase A — issued before the barrier) ----
    const size_t hw = (size_t)H * W;
    int   tR[TILES_PER_BLK], tC[TILES_PER_BLK];
    float pf0[TILES_PER_BLK], pf1[TILES_PER_BLK], pf2[TILES_PER_BLK];
    #pragma unroll
    for (int tt = 0; tt < TILES_PER_BLK; ++tt) {
        const int t  = L + tt * BLK_PER_IMG;     // 0..575
        const int tx = t % NTX, ty = t / NTX;
        tR[tt] = ty * TH + (tid >> 5);
        tC[tt] = tx * TW + (tid & 31);
        const size_t pix = (size_t)tR[tt] * W + tC[tt];
        const size_t imgbase = ((size_t)n * 4) * hw + pix;
        pf0[tt] = images[imgbase];
        pf1[tt] = images[imgbase + hw];
        pf2[tt] = images[imgbase + 2 * hw];
    }
    __syncthreads();

    const float col0 = colors[n * 4 + 0];
    const float col1 = colors[n * 4 + 1];
    const float col2 = colors[n * 4 + 2];

    const int lane   = tid & 63;
    const int p_lane = lane & 15;

    #pragma unroll
    for (int tt = 0; tt < TILES_PER_BLK; ++tt) {
        const int r = tR[tt];
        const int c = tC[tt];
        const float rf  = (float)r;
        const float cjf = (float)c;

        // ---- PER-WAVE ballot cull + interior classification: lane p tests
        // stroke p against this wave's 2-row x 32-col strip (affine corner
        // min AND max). keep: conservative (exact-zero iff u>=65 or v>=65;
        // margin 67 covers f32 deviation). interior: strict u,v in
        // (1.6,63.4) est => true u,v in (1.1,63.9) => clamps no-op,
        // indicators all 1 => fast path is BIT-IDENTICAL.
        const int c0w = c & ~31;                 // wave's col range start
        const int r0w = r & ~1;                  // wave's 2-row strip start
        bool keep = false, interior = false;
        {
            const float* P = sP + p_lane * PARAM_F;
            if (P[5] > 0.0f) {
                const float x = P[0], y = P[1], rs = P[2];
                const float ct = P[3], st = P[4];
                const float cLo = (float)c0w, cHi = (float)(c0w + 31);
                const float rLo = (float)r0w, rHi = (float)(r0w + 1);
                const float cuMin = (ct >= 0.0f) ? cLo : cHi;
                const float ruMin = (st >= 0.0f) ? rLo : rHi;
                const float cuMax = (ct >= 0.0f) ? cHi : cLo;
                const float ruMax = (st >= 0.0f) ? rHi : rLo;
                const float umin = (ct * (cuMin - x) + st * (ruMin - y)) * rs + 32.5f;
                const float umax = (ct * (cuMax - x) + st * (ruMax - y)) * rs + 32.5f;
                const float cvMin = (st <= 0.0f) ? cLo : cHi;
                const float rvMin = (ct >= 0.0f) ? rLo : rHi;
                const float cvMax = (st <= 0.0f) ? cHi : cLo;
                const float rvMax = (ct >= 0.0f) ? rHi : rLo;
                const float vmin = (-st * (cvMin - x) + ct * (rvMin - y)) * rs + 32.5f;
                const float vmax = (-st * (cvMax - x) + ct * (rvMax - y)) * rs + 32.5f;
                keep = (umin < 67.0f) && (vmin < 67.0f);
                interior = keep && (umin > 1.6f) && (umax < 63.4f)
                                && (vmin > 1.6f) && (vmax < 63.4f);
            }
        }
        const bool lane_ok = (lane < P_STR);
        const unsigned mask    = (unsigned)(__ballot(keep && lane_ok)     & 0xFFFFull);
        const unsigned maskInt = (unsigned)(__ballot(interior && lane_ok) & 0xFFFFull);

        float F0 = 1.0f - pf0[tt];
        float F1 = 1.0f - pf1[tt];
        float F2 = 1.0f - pf2[tt];

        for (int p = 0; p < P_STR; ++p) {
            if (!((mask >> p) & 1u)) continue;
            const float* P = sP + p * PARAM_F;   // broadcast LDS reads
            const float x  = P[0], y = P[1], rs = P[2];
            const float ct = P[3], st = P[4];
            const float nst = -st;               // reference: (-st) * dx
            const float dy  = rf - y;            // rows - y, f32
            const float tu  = st * dy;
            const float tv  = ct * dy;
            const float dx  = cjf - x;           // cols - x, f32

            // BIT-LOCKED per-pixel chain (identical ops to R13):
            float u = (ct * dx + tu) * rs;
            u = u + 31.5f; u = u + 1.0f;
            float v = (nst * dx + tv) * rs;
            v = v + 31.5f; v = v + 1.0f;

            const float u0f = floorf(u), v0f = floorf(v);
            const float du = u - u0f, dv = v - v0f;
            const int ui = (int)u0f, vi = (int)v0f;

            float av;
            if ((maskInt >> p) & 1u) {
                // FAST PATH (wave-uniform): ui in [1,63], vi in [1,63]
                // guaranteed => clamps no-op, M == 1 exactly.
                const int b0 = vi * LDSP + ui;
                const float a00 = s_alpha[b0],        a01 = s_alpha[b0 + 1];
                const float a10 = s_alpha[b0 + LDSP], a11 = s_alpha[b0 + LDSP + 1];
                const float ax0 = a00 + du * (a01 - a00);
                const float ax1 = a10 + du * (a11 - a10);
                av = ax0 + dv * (ax1 - ax0);
                const float inva = 1.0f - av;
                F0 = F0 * inva + (av - col0 * av);
                F1 = F1 * inva + (av - col1 * av);
                F2 = F2 * inva + (av - col2 * av);
            } else {
                const int u0c = min(max(ui, 0), PAD - 1);
                const int u1c = min(u0c + 1, PAD - 1);
                const int v0c = min(max(vi, 0), PAD - 1);
                const int v1c = min(v0c + 1, PAD - 1);

                const float inu0 = ((unsigned)(u0c - 1) < 64u) ? 1.0f : 0.0f;
                const float inu1 = ((unsigned)(u1c - 1) < 64u) ? 1.0f : 0.0f;
                const float inv0 = ((unsigned)(v0c - 1) < 64u) ? 1.0f : 0.0f;
                const float inv1 = ((unsigned)(v1c - 1) < 64u) ? 1.0f : 0.0f;
                const float mu = inu0 + du * (inu1 - inu0);
                const float mv = inv0 + dv * (inv1 - inv0);
                const float M  = mu * mv;

                const int b0 = v0c * LDSP, b1 = v1c * LDSP;
                const float a00 = s_alpha[b0 + u0c], a01 = s_alpha[b0 + u1c];
                const float a10 = s_alpha[b1 + u0c], a11 = s_alpha[b1 + u1c];
                const float ax0 = a00 + du * (a01 - a00);
                const float ax1 = a10 + du * (a11 - a10);
                av = ax0 + dv * (ax1 - ax0);

                const float inva = 1.0f - av;
                const float am   = av * M;
                F0 = F0 * inva + (av - col0 * am);
                F1 = F1 * inva + (av - col1 * am);
                F2 = F2 * inva + (av - col2 * am);
            }
        }

        const size_t pix = (size_t)r * W + c;
        const size_t outbase = ((size_t)n * 3) * hw + pix;
        out[outbase]          = 1.0f - F0;
        out[outbase + hw]     = 1.0f - F1;
        out[outbase + 2 * hw] = 1.0f - F2;
    }
}

extern "C" void kernel_launch(void* const* d_in, const int* in_sizes, int n_in,
                              void* d_out, int out_size, void* d_ws, size_t ws_size,
                              hipStream_t stream) {
    (void)in_sizes; (void)n_in; (void)d_ws; (void)ws_size; (void)out_size;
    const float* images = (const float*)d_in[0];
    const float* knot_t = (const float*)d_in[1];
    const float* a_     = (const float*)d_in[2];
    const float* b_     = (const float*)d_in[3];
    const float* c2_    = (const float*)d_in[4];
    const float* d3_    = (const float*)d_in[5];
    const float* colors = (const float*)d_in[6];
    const float* ts     = (const float*)d_in[7];
    const float* brush  = (const float*)d_in[8];
    float* out = (float*)d_out;

    hipLaunchKernelGGL(blit_fused, dim3(BLK_PER_IMG, 1, 4), dim3(256), 0, stream,
                       images, knot_t, a_, b_, c2_, d3_, colors, ts, brush, out);
}

// Round 23
// 21.834 us; speedup vs baseline: 1.0157x; 1.0157x over previous
//
#include <hip/hip_runtime.h>
#include <math.h>

#pragma clang fp contract(off)

namespace {
constexpr int P_STR  = 16;   // strokes per image
constexpr int K_KNOT = 8;
constexpr int H = 384;
constexpr int W = 384;
constexpr int BH = 64;
constexpr int BW = 64;
constexpr int TW = 32;       // tile width (cols)
constexpr int TH = 8;        // tile height (rows)
constexpr int NTX = W / TW;  // 12
constexpr int NTY = H / TH;  // 48
constexpr int NTILES = NTX * NTY;        // 576 per image
constexpr int BLK_PER_IMG = 288;         // persistent blocks per image
constexpr int TILES_PER_BLK = NTILES / BLK_PER_IMG;  // 2
constexpr int PAD = 66;      // logical padded extent (64 + 2)
constexpr int LDSP = 67;     // pitch: odd -> coprime with 32 banks
constexpr int AFLOATS = 66 * LDSP + 2;   // 4424 floats
constexpr int PARAM_F = 8;   // floats per stroke param slot
}

// ---- faithful port of glibc sysdeps/ieee754/flt-32/s_atanf.c (fdlibm) ----
__device__ __forceinline__ float fdlibm_atanf_plain(float x)
{
#pragma clang fp contract(off)
    const float atanhi0 = 4.6364760399e-01f, atanhi1 = 7.8539812565e-01f,
                atanhi2 = 9.8279368877e-01f, atanhi3 = 1.5707962513e+00f;
    const float atanlo0 = 5.0121582440e-09f, atanlo1 = 3.7748947079e-08f,
                atanlo2 = 3.4473217170e-08f, atanlo3 = 7.5497894159e-08f;
    const float aT0 = 3.3333328366e-01f, aT1 = -1.9999158382e-01f,
                aT2 = 1.4253635705e-01f, aT3 = -1.0648017377e-01f,
                aT4 = 6.1687607318e-02f;
    const float one = 1.0f;

    const int hx = __float_as_int(x);
    const int ix = hx & 0x7fffffff;
    int id;
    if (ix >= 0x4c800000) {           // |x| >= 2^26
        if (ix > 0x7f800000) return x + x;   // NaN
        return (hx > 0) ? (atanhi3 + atanlo3) : (-atanhi3 - atanlo3);
    }
    if (ix < 0x3ee00000) {            // |x| < 0.4375
        if (ix < 0x39800000) return x;       // |x| < 2^-12
        id = -1;
    } else {
        x = fabsf(x);
        if (ix < 0x3f980000) {        // |x| < 1.1875
            if (ix < 0x3f300000) {    // 7/16 <= |x| < 11/16
                id = 0; x = (2.0f * x - one) / (2.0f + x);
            } else {                  // 11/16 <= |x| < 19/16
                id = 1; x = (x - one) / (x + one);
            }
        } else {
            if (ix < 0x401c0000) {    // |x| < 2.4375
                id = 2; x = (x - 1.5f) / (one + 1.5f * x);
            } else {                  // 2.4375 <= |x|
                id = 3; x = -1.0f / x;
            }
        }
    }
    const float z = x * x;
    const float w = z * z;
    const float s1 = z * (aT0 + w * (aT2 + w * aT4));
    const float s2 = w * (aT1 + w * aT3);
    if (id < 0) return x - x * (s1 + s2);
    const float ahi = (id == 0) ? atanhi0 : (id == 1) ? atanhi1 : (id == 2) ? atanhi2 : atanhi3;
    const float alo = (id == 0) ? atanlo0 : (id == 1) ? atanlo1 : (id == 2) ? atanlo2 : atanlo3;
    const float zz = ahi - ((x * (s1 + s2) - alo) - x);
    return (hx < 0) ? -zz : zz;
}

// ---- faithful port of glibc sysdeps/ieee754/flt-32/e_atan2f.c (fdlibm) ----
__device__ __forceinline__ float fdlibm_atan2f_plain(float y, float x)
{
#pragma clang fp contract(off)
    const float pi_o_2 = 1.5707963705e+00f;   // 0x3FC90FDB
    const float pi_    = 3.1415927410e+00f;   // 0x40490FDB
    const float pi_lo  = -8.7422776573e-08f;  // 0xB3BBBD2E

    const int hx = __float_as_int(x), hy = __float_as_int(y);
    const int ix = hx & 0x7fffffff, iy = hy & 0x7fffffff;
    if (ix > 0x7f800000 || iy > 0x7f800000) return x + y;   // NaN
    if (hx == 0x3f800000) return fdlibm_atanf_plain(y);     // x == 1.0
    int m = ((hy >> 31) & 1) | ((hx >> 30) & 2);

    if (iy == 0) {
        switch (m) {
            case 0: case 1: return y;
            case 2: return pi_;
            default: return -pi_;
        }
    }
    if (ix == 0) return (hy < 0) ? -pi_o_2 : pi_o_2;
    if (ix == 0x7f800000) {
        if (iy == 0x7f800000) {
            switch (m) {
                case 0: return  pi_o_2 * 0.5f;
                case 1: return -pi_o_2 * 0.5f;
                case 2: return  3.0f * pi_o_2 * 0.5f;
                default: return -3.0f * pi_o_2 * 0.5f;
            }
        }
        switch (m) {
            case 0: return 0.0f;
            case 1: return -0.0f;
            case 2: return pi_;
            default: return -pi_;
        }
    }
    if (iy == 0x7f800000) return (hy < 0) ? -pi_o_2 : pi_o_2;

    const int k = (iy - ix) >> 23;
    float z;
    if (k > 26) {                    // |y/x| > 2^26
        z = pi_o_2 + 0.5f * pi_lo;
        m &= 1;
    } else if (hx < 0 && k < -26) {  // |y|/x < -2^26
        z = 0.0f;
    } else {
        z = fdlibm_atanf_plain(fabsf(y / x));
    }
    switch (m) {
        case 0: return z;
        case 1: return -z;
        case 2: return pi_ - (z - pi_lo);
        default: return (z - pi_lo) - pi_;
    }
}

// ==== fused: phase A (wave 0) ∥ alpha staging (waves 1-3), then composite ====
__global__ __launch_bounds__(256) void blit_fused(
    const float* __restrict__ images, const float* __restrict__ knot_t,
    const float* __restrict__ a_,     const float* __restrict__ b_,
    const float* __restrict__ c2_,    const float* __restrict__ d3_,
    const float* __restrict__ colors, const float* __restrict__ ts,
    const float* __restrict__ brush,  float* __restrict__ out)
{
#pragma clang fp contract(off)
    __shared__ float sP[P_STR * PARAM_F];            // 128 floats
    __shared__ __align__(8) float s_alpha[AFLOATS];  // 4424 floats, pitch 67

    const int n   = blockIdx.z;
    const int L   = blockIdx.x;          // 0..287
    const int tid = threadIdx.x;

    const float c3 = colors[n * 4 + 3];

    // ---- Phase A on wave 0 lanes 0..15 (BIT-LOCKED R13 math, unchanged) ----
    if (tid < P_STR) {
        const int p = tid;
        const float t = ts[p];
        int ins = 0;
        #pragma unroll
        for (int i = 0; i < K_KNOT; ++i) ins += (knot_t[i] <= t) ? 1 : 0;
        const int idx = min(max(ins - 1, 0), K_KNOT - 2);
        const float f = t - knot_t[idx];

        const int base = (n * (K_KNOT - 1) + idx) * 3;
        const float C3INV = 0.3333333432674408f;   // 0x3EAAAAAB
        float q[3], qd[3];
        #pragma unroll
        for (int j = 0; j < 3; ++j) {
            const float aj = a_[base + j], bj = b_[base + j];
            const float cj = c2_[base + j], dj = d3_[base + j];
            const float inner = cj * 0.5f + (dj * f) * C3INV;
            q[j]  = aj + (bj + inner * f) * f;
            qd[j] = bj + (cj + dj * f) * f;
        }
        const float x = q[0], y = q[1], z = q[2];
        const float s = fminf(fmaxf(z, 0.001f), 1.0f);

        const float apos = fdlibm_atan2f_plain(qd[1], qd[0]);
        const float thf  = -apos;
        const float ct_  = (float)cos((double)thf);
        const float st_  = (float)sin((double)thf);

        float* P = sP + p * PARAM_F;
        P[0] = x; P[1] = y; P[2] = 1.0f / s;   // reciprocal rounded ONCE
        P[3] = ct_; P[4] = st_;
        P[5] = (z > 0.0f) ? 1.0f : 0.0f;
    }

    // ---- alpha staging on waves 1..3 (independent of params; overlaps trig) ----
    if (tid >= 64) {
        for (int i = tid - 64; i < AFLOATS; i += 192) {
            const int v = i / LDSP;
            const int u = i - v * LDSP;
            float val = 0.0f;
            if ((unsigned)(v - 1) < (unsigned)BH && (unsigned)(u - 1) < (unsigned)BW)
                val = brush[3 * BH * BW + (v - 1) * BW + (u - 1)] * c3;
            s_alpha[i] = val;
        }
    }

    // ---- image PREFETCH for both tiles (independent of LDS; overlaps
    //      staging + Phase A — issued before the barrier) ----
    const size_t hw = (size_t)H * W;
    int   tR[TILES_PER_BLK], tC[TILES_PER_BLK];
    float pf0[TILES_PER_BLK], pf1[TILES_PER_BLK], pf2[TILES_PER_BLK];
    #pragma unroll
    for (int tt = 0; tt < TILES_PER_BLK; ++tt) {
        const int t  = L + tt * BLK_PER_IMG;     // 0..575
        const int tx = t % NTX, ty = t / NTX;
        tR[tt] = ty * TH + (tid >> 5);
        tC[tt] = tx * TW + (tid & 31);
        const size_t pix = (size_t)tR[tt] * W + tC[tt];
        const size_t imgbase = ((size_t)n * 4) * hw + pix;
        pf0[tt] = images[imgbase];
        pf1[tt] = images[imgbase + hw];
        pf2[tt] = images[imgbase + 2 * hw];
    }
    __syncthreads();

    const float col0 = colors[n * 4 + 0];
    const float col1 = colors[n * 4 + 1];
    const float col2 = colors[n * 4 + 2];

    const int lane   = tid & 63;
    const int p_lane = lane & 15;

    #pragma unroll
    for (int tt = 0; tt < TILES_PER_BLK; ++tt) {
        const int r = tR[tt];
        const int c = tC[tt];
        const float rf  = (float)r;
        const float cjf = (float)c;

        // ---- PER-WAVE ballot cull: lane p tests stroke p against this
        // wave's own 2-row x 32-col strip. Conservative: sample == 0 exactly
        // iff u>=65 or v>=65; margin 67.0 covers f32 deviation.
        const int c0w = c & ~31;                 // wave's col range start
        const int r0w = r & ~1;                  // wave's 2-row strip start
        bool keep = false;
        {
            const float* P = sP + p_lane * PARAM_F;
            if (P[5] > 0.0f) {
                const float x = P[0], y = P[1], rs = P[2];
                const float ct = P[3], st = P[4];
                const float cLo = (float)c0w, cHi = (float)(c0w + 31);
                const float rLo = (float)r0w, rHi = (float)(r0w + 1);
                const float cu = (ct >= 0.0f) ? cLo : cHi;
                const float ru = (st >= 0.0f) ? rLo : rHi;
                const float umin = (ct * (cu - x) + st * (ru - y)) * rs + 32.5f;
                const float cv = (st <= 0.0f) ? cLo : cHi;
                const float rv = (ct >= 0.0f) ? rLo : rHi;
                const float vmin = (-st * (cv - x) + ct * (rv - y)) * rs + 32.5f;
                keep = (umin < 67.0f) && (vmin < 67.0f);
            }
        }
        const unsigned mask =
            (unsigned)(__ballot(keep && (lane < P_STR)) & 0xFFFFull);

        float F0 = 1.0f - pf0[tt];
        float F1 = 1.0f - pf1[tt];
        float F2 = 1.0f - pf2[tt];

        for (int p = 0; p < P_STR; ++p) {
            if (!((mask >> p) & 1u)) continue;
            const float* P = sP + p * PARAM_F;   // broadcast LDS reads
            const float x  = P[0], y = P[1], rs = P[2];
            const float ct = P[3], st = P[4];
            const float nst = -st;               // reference: (-st) * dx
            const float dy  = rf - y;            // rows - y, f32
            const float tu  = st * dy;
            const float tv  = ct * dy;
            const float dx  = cjf - x;           // cols - x, f32

            // BIT-LOCKED per-pixel chain (identical ops to R13):
            float u = (ct * dx + tu) * rs;
            u = u + 31.5f; u = u + 1.0f;
            float v = (nst * dx + tv) * rs;
            v = v + 31.5f; v = v + 1.0f;

            const float u0f = floorf(u), v0f = floorf(v);
            const float du = u - u0f, dv = v - v0f;
            const int ui = (int)u0f, vi = (int)v0f;
            const int u0c = min(max(ui, 0), PAD - 1);
            const int u1c = min(u0c + 1, PAD - 1);
            const int v0c = min(max(vi, 0), PAD - 1);
            const int v1c = min(v0c + 1, PAD - 1);

            const float inu0 = ((unsigned)(u0c - 1) < 64u) ? 1.0f : 0.0f;
            const float inu1 = ((unsigned)(u1c - 1) < 64u) ? 1.0f : 0.0f;
            const float inv0 = ((unsigned)(v0c - 1) < 64u) ? 1.0f : 0.0f;
            const float inv1 = ((unsigned)(v1c - 1) < 64u) ? 1.0f : 0.0f;
            const float mu = inu0 + du * (inu1 - inu0);
            const float mv = inv0 + dv * (inv1 - inv0);
            const float M  = mu * mv;

            const int b0 = v0c * LDSP, b1 = v1c * LDSP;
            const float a00 = s_alpha[b0 + u0c], a01 = s_alpha[b0 + u1c];
            const float a10 = s_alpha[b1 + u0c], a11 = s_alpha[b1 + u1c];
            const float ax0 = a00 + du * (a01 - a00);
            const float ax1 = a10 + du * (a11 - a10);
            const float av  = ax0 + dv * (ax1 - ax0);

            const float inva = 1.0f - av;
            const float am   = av * M;
            F0 = F0 * inva + (av - col0 * am);
            F1 = F1 * inva + (av - col1 * am);
            F2 = F2 * inva + (av - col2 * am);
        }

        const size_t pix = (size_t)r * W + c;
        const size_t outbase = ((size_t)n * 3) * hw + pix;
        out[outbase]          = 1.0f - F0;
        out[outbase + hw]     = 1.0f - F1;
        out[outbase + 2 * hw] = 1.0f - F2;
    }
}

extern "C" void kernel_launch(void* const* d_in, const int* in_sizes, int n_in,
                              void* d_out, int out_size, void* d_ws, size_t ws_size,
                              hipStream_t stream) {
    (void)in_sizes; (void)n_in; (void)d_ws; (void)ws_size; (void)out_size;
    const float* images = (const float*)d_in[0];
    const float* knot_t = (const float*)d_in[1];
    const float* a_     = (const float*)d_in[2];
    const float* b_     = (const float*)d_in[3];
    const float* c2_    = (const float*)d_in[4];
    const float* d3_    = (const float*)d_in[5];
    const float* colors = (const float*)d_in[6];
    const float* ts     = (const float*)d_in[7];
    const float* brush  = (const float*)d_in[8];
    float* out = (float*)d_out;

    hipLaunchKernelGGL(blit_fused, dim3(BLK_PER_IMG, 1, 4), dim3(256), 0, stream,
                       images, knot_t, a_, b_, c2_, d3_, colors, ts, brush, out);
}